// Round 7
// baseline (462.116 us; speedup 1.0000x reference)
//
#include <hip/hip_runtime.h>

// CRF forward (partition fn), B=512, T=512, L=102 (start=100, stop=101).
// R7: ONE wave (64 threads) per batch element -- zero barriers; lane owns
// rows 2*lane, 2*lane+1. Mexp = exp(trans[j,:]-rowmax[j]) as 104 named
// half2 VGPRs (2 rows x 52). P f16 in LDS (double-buffered, broadcast
// b128 reads). Per-step uniform shift with 1-step-delayed max, reduced via
// DPP (VALU, ~5 cyc/hop) + readlane instead of 6 DS-shuffles (~100 cyc/hop)
// -- that chain + __syncthreads drain was R6's 1640 cyc/step.
// NOTE (R6 errata): FETCH_SIZE is KB -> 27 MB total; memory was never the
// bottleneck. This kernel is critical-path latency bound.

typedef _Float16 half2_t __attribute__((ext_vector_type(2)));

#define CRF_L 102
#define CRF_RP 104          // padded LDS row stride (floats) for trans
#define CRF_START 100
#define CRF_STOP 101
#define NEG_BIG (-1.0e30f)
#define DRIFT_ALLOW 6.0f

#define REP13(X) X(0) X(1) X(2) X(3) X(4) X(5) X(6) X(7) X(8) X(9) X(10) X(11) X(12)

#define FDOT2(a, b, c) __builtin_amdgcn_fdot2((a), (b), (c), false)

template <int CTRL>
__device__ __forceinline__ float dpp_max_step(float x) {
    int xi = __builtin_bit_cast(int, x);
    int yi = __builtin_amdgcn_update_dpp(xi, xi, CTRL, 0xf, 0xf, false);
    return fmaxf(x, __builtin_bit_cast(float, yi));
}
template <int CTRL>
__device__ __forceinline__ float dpp_add_step(float x) {
    int xi = __builtin_bit_cast(int, x);
    int yi = __builtin_amdgcn_update_dpp(0, xi, CTRL, 0xf, 0xf, true);
    return x + __builtin_bit_cast(float, yi);
}
// full-wave64 max/sum, result uniform via readlane(63)
__device__ __forceinline__ float wave_max64(float v) {
    v = dpp_max_step<0x111>(v);  // row_shr:1
    v = dpp_max_step<0x112>(v);  // row_shr:2
    v = dpp_max_step<0x114>(v);  // row_shr:4
    v = dpp_max_step<0x118>(v);  // row_shr:8
    v = dpp_max_step<0x142>(v);  // row_bcast:15
    v = dpp_max_step<0x143>(v);  // row_bcast:31
    return __builtin_bit_cast(float,
        __builtin_amdgcn_readlane(__builtin_bit_cast(int, v), 63));
}
__device__ __forceinline__ float wave_sum64(float v) {
    v = dpp_add_step<0x111>(v);
    v = dpp_add_step<0x112>(v);
    v = dpp_add_step<0x114>(v);
    v = dpp_add_step<0x118>(v);
    v = dpp_add_step<0x142>(v);
    v = dpp_add_step<0x143>(v);
    return __builtin_bit_cast(float,
        __builtin_amdgcn_readlane(__builtin_bit_cast(int, v), 63));
}

__device__ __forceinline__ half2_t mk2(const float* rowp, int k, float rmx) {
    float e0 = (k + 0 < CRF_L) ? __expf(rowp[k + 0] - rmx) : 0.f;
    float e1 = (k + 1 < CRF_L) ? __expf(rowp[k + 1] - rmx) : 0.f;
    return (half2_t){(_Float16)e0, (_Float16)e1};
}

__attribute__((amdgpu_waves_per_eu(1, 1)))
__launch_bounds__(64)
__global__ void crf_forward_kernel(const float* __restrict__ logits,
                                   const float* __restrict__ trans,
                                   const int* __restrict__ lens,
                                   float* __restrict__ out,
                                   int B, int T) {
    const int b    = blockIdx.x;
    const int lane = threadIdx.x;          // 0..63
    const int r0   = 2 * lane;
    const int r1   = 2 * lane + 1;
    const bool valid = (lane < 51);        // rows 0..101

    __shared__ __align__(16) float TS[CRF_L * CRF_RP];   // trans, padded rows
    __shared__ __align__(16) _Float16 Pb[2][112];        // 13 float4 each

    // ---- stage trans into LDS (coalesced global reads) ----
    #pragma unroll 4
    for (int r = 0; r < CRF_L; ++r)
        for (int c = lane; c < CRF_L; c += 64)
            TS[CRF_RP * r + c] = trans[CRF_L * r + c];

    // ---- init P buffers (both, incl. pad tails) ----
    if (lane < 56) {
        int i0 = 2 * lane, i1 = 2 * lane + 1;
        Pb[0][i0] = (_Float16)((i0 == CRF_START) ? 1.f : 0.f);
        Pb[0][i1] = (_Float16)0.f;
        Pb[1][i0] = (_Float16)0.f;
        Pb[1][i1] = (_Float16)0.f;
    }
    __builtin_amdgcn_wave_barrier();   // order LDS init vs reads (wave-sync HW)

    // ---- rowmax + pack Mexp into 104 named half2 registers ----
    const float* rowA = &TS[CRF_RP * (valid ? r0 : 0)];
    const float* rowB = &TS[CRF_RP * (valid ? r1 : 0)];
    float rmax0 = NEG_BIG, rmax1 = NEG_BIG;
    #pragma unroll
    for (int k = 0; k < CRF_L; ++k) {
        rmax0 = fmaxf(rmax0, rowA[k]);
        rmax1 = fmaxf(rmax1, rowB[k]);
    }

#define DECLM(j) half2_t ma##j##_0, ma##j##_1, ma##j##_2, ma##j##_3, \
                         mb##j##_0, mb##j##_1, mb##j##_2, mb##j##_3;
    REP13(DECLM)
#undef DECLM
#define PACKJ(j) \
    ma##j##_0 = mk2(rowA, 8*(j)+0, rmax0); ma##j##_1 = mk2(rowA, 8*(j)+2, rmax0); \
    ma##j##_2 = mk2(rowA, 8*(j)+4, rmax0); ma##j##_3 = mk2(rowA, 8*(j)+6, rmax0); \
    mb##j##_0 = mk2(rowB, 8*(j)+0, rmax1); mb##j##_1 = mk2(rowB, 8*(j)+2, rmax1); \
    mb##j##_2 = mk2(rowB, 8*(j)+4, rmax1); mb##j##_3 = mk2(rowB, 8*(j)+6, rmax1);
    REP13(PACKJ)
#undef PACKJ

    // ---- state: alpha_j = g_j + base; P = exp(g - Sused); Epend = max arg ----
    float g0 = valid ? ((r0 == CRF_START) ? 0.f : -10000.f) : NEG_BIG;
    float g1 = valid ? ((r1 == CRF_START) ? 0.f : -10000.f) : NEG_BIG;
    float base = 0.f, Sused = 0.f, Epend = 0.f;

    const int len = min(lens[b], T);
    const float* lg = logits + (size_t)b * (size_t)T * (size_t)CRF_L;
    const int loff = valid ? r0 : 0;

    // depth-2 logit prefetch (float2, coalesced)
    float2 lgA = *reinterpret_cast<const float2*>(lg + loff);
    float2 lgB = *reinterpret_cast<const float2*>(lg + (size_t)min(1, T - 1) * CRF_L + loff);

    for (int t = 0; t < len; ++t) {
        float2 lo = lgA;
        lgA = lgB;
        lgB = *reinterpret_cast<const float2*>(lg + (size_t)min(t + 2, T - 1) * CRF_L + loff);

        // ---- dot(Mexp[r,:], P[:]) both rows: 13 b128 broadcasts, 104 dot2 ----
        const float4* P4 = reinterpret_cast<const float4*>(&Pb[t & 1][0]);
        float c0 = 0.f, c1 = 0.f, c2 = 0.f, c3 = 0.f;
        float d0 = 0.f, d1 = 0.f, d2 = 0.f, d3 = 0.f;
#define DOT(j) { float4 q = P4[j]; \
        half2_t q0 = __builtin_bit_cast(half2_t, q.x); \
        half2_t q1 = __builtin_bit_cast(half2_t, q.y); \
        half2_t q2 = __builtin_bit_cast(half2_t, q.z); \
        half2_t q3 = __builtin_bit_cast(half2_t, q.w); \
        c0 = FDOT2(ma##j##_0, q0, c0); c1 = FDOT2(ma##j##_1, q1, c1); \
        c2 = FDOT2(ma##j##_2, q2, c2); c3 = FDOT2(ma##j##_3, q3, c3); \
        d0 = FDOT2(mb##j##_0, q0, d0); d1 = FDOT2(mb##j##_1, q1, d1); \
        d2 = FDOT2(mb##j##_2, q2, d2); d3 = FDOT2(mb##j##_3, q3, d3); }
        REP13(DOT)
#undef DOT
        float dot0 = fmaxf((c0 + c1) + (c2 + c3), 1e-37f);
        float dot1 = fmaxf((d0 + d1) + (d2 + d3), 1e-37f);

        float gn0 = lo.x + rmax0 + __logf(dot0);
        float gn1 = lo.y + rmax1 + __logf(dot1);
        g0 = valid ? gn0 : NEG_BIG;
        g1 = valid ? gn1 : NEG_BIG;

        base += Sused;                       // alpha = g + base
        float Snew = Epend + DRIFT_ALLOW;    // 1-step-delayed shift (R6-proven)
        float arg0 = g0 - Snew;
        float arg1 = g1 - Snew;

        if (valid) {
            half2_t pp = (half2_t){(_Float16)__expf(arg0), (_Float16)__expf(arg1)};
            *reinterpret_cast<half2_t*>(&Pb[(t + 1) & 1][r0]) = pp;
        }
        Sused = Snew;

        // max of exp-args via DPP (VALU) -- no DS ops, no barrier
        Epend = wave_max64(valid ? fmaxf(arg0, arg1) : NEG_BIG);
        __builtin_amdgcn_wave_barrier();     // pin loop-iteration ordering
    }

    // ---- epilogue: alpha += trans[STOP,:]; out[b] = LSE ----
    float ts0 = TS[CRF_RP * CRF_STOP + (valid ? r0 : 0)];
    float ts1 = TS[CRF_RP * CRF_STOP + (valid ? r1 : 0)];
    float av0 = valid ? (g0 + base + ts0) : NEG_BIG;
    float av1 = valid ? (g1 + base + ts1) : NEG_BIG;

    float fm = wave_max64(fmaxf(av0, av1));
    float e  = valid ? (__expf(av0 - fm) + __expf(av1 - fm)) : 0.f;
    float se = wave_sum64(e);

    if (lane == 0) out[b] = fm + __logf(se);
}

extern "C" void kernel_launch(void* const* d_in, const int* in_sizes, int n_in,
                              void* d_out, int out_size, void* d_ws, size_t ws_size,
                              hipStream_t stream) {
    const float* logits = (const float*)d_in[0];   // [B, T, L] fp32
    const float* trans  = (const float*)d_in[1];   // [L, L] fp32
    const int*   lens   = (const int*)d_in[2];     // [B] int32
    float* out = (float*)d_out;                    // [B] fp32

    const int B = 512;
    const int T = 512;

    crf_forward_kernel<<<dim3(B), dim3(64), 0, stream>>>(
        logits, trans, lens, out, B, T);
}

// Round 8
// 410.752 us; speedup vs baseline: 1.1250x; 1.1250x over previous
//
#include <hip/hip_runtime.h>

// CRF forward (partition fn), B=512, T=512, L=102 (start=100, stop=101).
// R8: LINEAR-DOMAIN recurrence -- no log/exp on the per-step serial path.
//   Q_t[j] = E_j(t) * sum_k Mhat[j,k] Q_{t-1}[k] * rcp(R)*2^-8
// where Mhat = exp(trans - rowmax_j) (104 named half2 VGPRs, shared work),
// E_j(t) = exp(logit[t,j] + rowmax_j) computed 2 steps ahead (off-path),
// R = sum_j Q (DPP sum in the shadow, factor exactly logged into Lacc).
// Serial path per step: ds_read Q -> 104 dot2 -> 2 mul -> cvt -> ds_write.
// One wave per batch element, zero barriers.

typedef _Float16 half2_t __attribute__((ext_vector_type(2)));

#define CRF_L 102
#define CRF_RP 104
#define CRF_START 100
#define CRF_STOP 101
#define NEG_BIG (-1.0e30f)
#define LN2F 0.6931471805599453f

#define REP13(X) X(0) X(1) X(2) X(3) X(4) X(5) X(6) X(7) X(8) X(9) X(10) X(11) X(12)

#define FDOT2(a, b, c) __builtin_amdgcn_fdot2((a), (b), (c), false)

template <int CTRL>
__device__ __forceinline__ float dpp_add_step(float x) {
    int xi = __builtin_bit_cast(int, x);
    int yi = __builtin_amdgcn_update_dpp(0, xi, CTRL, 0xf, 0xf, true);
    return x + __builtin_bit_cast(float, yi);
}
__device__ __forceinline__ float wave_sum64(float v) {
    v = dpp_add_step<0x111>(v);  // row_shr:1
    v = dpp_add_step<0x112>(v);  // row_shr:2
    v = dpp_add_step<0x114>(v);  // row_shr:4
    v = dpp_add_step<0x118>(v);  // row_shr:8
    v = dpp_add_step<0x142>(v);  // row_bcast:15
    v = dpp_add_step<0x143>(v);  // row_bcast:31
    return __builtin_bit_cast(float,
        __builtin_amdgcn_readlane(__builtin_bit_cast(int, v), 63));
}

__device__ __forceinline__ half2_t mk2(const float* rowp, int k, float rmx) {
    float e0 = (k + 0 < CRF_L) ? __expf(rowp[k + 0] - rmx) : 0.f;
    float e1 = (k + 1 < CRF_L) ? __expf(rowp[k + 1] - rmx) : 0.f;
    return (half2_t){(_Float16)e0, (_Float16)e1};
}

__attribute__((amdgpu_waves_per_eu(1, 1)))
__launch_bounds__(64)
__global__ void crf_forward_kernel(const float* __restrict__ logits,
                                   const float* __restrict__ trans,
                                   const int* __restrict__ lens,
                                   float* __restrict__ out,
                                   int B, int T) {
    const int b    = blockIdx.x;
    const int lane = threadIdx.x;          // 0..63
    const int r0   = 2 * lane;
    const int r1   = 2 * lane + 1;
    const bool valid = (lane < 51);        // rows 0..101

    __shared__ __align__(16) float TS[CRF_L * CRF_RP];   // trans, padded rows
    __shared__ __align__(16) _Float16 Q[112];            // 13 float4 read span

    // ---- stage trans into LDS (coalesced, setup-only) ----
    #pragma unroll 4
    for (int r = 0; r < CRF_L; ++r)
        for (int c = lane; c < CRF_L; c += 64)
            TS[CRF_RP * r + c] = trans[CRF_L * r + c];

    // ---- init Q (all 112 slots; Q0 = onehot(START)) ----
    if (lane < 56) {
        int i0 = 2 * lane;
        Q[i0]     = (_Float16)((i0 == CRF_START) ? 1.f : 0.f);
        Q[i0 + 1] = (_Float16)0.f;
    }
    __builtin_amdgcn_wave_barrier();

    // ---- rowmax + pack Mhat into 104 named half2 registers ----
    const float* rowA = &TS[CRF_RP * (valid ? r0 : 0)];
    const float* rowB = &TS[CRF_RP * (valid ? r1 : 0)];
    float rmax0 = NEG_BIG, rmax1 = NEG_BIG;
    #pragma unroll
    for (int k = 0; k < CRF_L; ++k) {
        rmax0 = fmaxf(rmax0, rowA[k]);
        rmax1 = fmaxf(rmax1, rowB[k]);
    }

#define DECLM(j) half2_t ma##j##_0, ma##j##_1, ma##j##_2, ma##j##_3, \
                         mb##j##_0, mb##j##_1, mb##j##_2, mb##j##_3;
    REP13(DECLM)
#undef DECLM
#define PACKJ(j) \
    ma##j##_0 = mk2(rowA, 8*(j)+0, rmax0); ma##j##_1 = mk2(rowA, 8*(j)+2, rmax0); \
    ma##j##_2 = mk2(rowA, 8*(j)+4, rmax0); ma##j##_3 = mk2(rowA, 8*(j)+6, rmax0); \
    mb##j##_0 = mk2(rowB, 8*(j)+0, rmax1); mb##j##_1 = mk2(rowB, 8*(j)+2, rmax1); \
    mb##j##_2 = mk2(rowB, 8*(j)+4, rmax1); mb##j##_3 = mk2(rowB, 8*(j)+6, rmax1);
    REP13(PACKJ)
#undef PACKJ

    // E uses logit + rowmax; invalid rows get -inf so E==0 (kills all selects)
    const float erm0 = (valid)              ? rmax0 : NEG_BIG;  // rows 102/103
    const float erm1 = (valid && r1 < CRF_L) ? rmax1 : NEG_BIG;

    const int len = min(lens[b], T);
    const float* lg = logits + (size_t)b * (size_t)T * (size_t)CRF_L;
    const int loff = valid ? r0 : 0;

    // depth-3 logit prefetch; E computed one step before use (off-path)
    float2 l0 = *reinterpret_cast<const float2*>(lg + loff);
    float2 lgB = *reinterpret_cast<const float2*>(lg + (size_t)min(1, T - 1) * CRF_L + loff);
    float2 lgC = *reinterpret_cast<const float2*>(lg + (size_t)min(2, T - 1) * CRF_L + loff);
    float2 Ec = make_float2(__expf(l0.x + erm0), __expf(l0.y + erm1));

    // scale bookkeeping: invRs/log2Rs prepared for next use; Lacc accumulates
    float invRs = 0.00390625f;   // 2^-8 * rcp(sum Q0 = 1)
    float log2Rs = 0.f;
    float Lacc = 0.f;
    float q0 = 0.f, q1 = 0.f;
    const int sidx = min(r0, 102);   // lanes >=52 alias the zero pad (benign)

    for (int t = 0; t < len; ++t) {
        // ---- dot(Mhat[r,:], Q[:]) both rows: 13 b128 broadcasts, 104 dot2 ----
        const float4* P4 = reinterpret_cast<const float4*>(&Q[0]);
        float c0 = 0.f, c1 = 0.f, c2 = 0.f, c3 = 0.f;
        float d0 = 0.f, d1 = 0.f, d2 = 0.f, d3 = 0.f;
#define DOT(j) { float4 q = P4[j]; \
        half2_t q0h = __builtin_bit_cast(half2_t, q.x); \
        half2_t q1h = __builtin_bit_cast(half2_t, q.y); \
        half2_t q2h = __builtin_bit_cast(half2_t, q.z); \
        half2_t q3h = __builtin_bit_cast(half2_t, q.w); \
        c0 = FDOT2(ma##j##_0, q0h, c0); c1 = FDOT2(ma##j##_1, q1h, c1); \
        c2 = FDOT2(ma##j##_2, q2h, c2); c3 = FDOT2(ma##j##_3, q3h, c3); \
        d0 = FDOT2(mb##j##_0, q0h, d0); d1 = FDOT2(mb##j##_1, q1h, d1); \
        d2 = FDOT2(mb##j##_2, q2h, d2); d3 = FDOT2(mb##j##_3, q3h, d3); }
        REP13(DOT)
#undef DOT
        float dot0 = (c0 + c1) + (c2 + c3);
        float dot1 = (d0 + d1) + (d2 + d3);

        // ---- linear-domain update; E and invRs were prepared off-path ----
        Lacc += log2Rs + 8.0f;               // factor R*2^8 applied this step
        q0 = (dot0 * Ec.x) * invRs;
        q1 = (dot1 * Ec.y) * invRs;

        __builtin_amdgcn_wave_barrier();     // all dot reads done (lockstep)
        *reinterpret_cast<half2_t*>(&Q[sidx]) =
            (half2_t){(_Float16)q0, (_Float16)q1};
        __builtin_amdgcn_wave_barrier();

        // ---- shadow work for NEXT step (off the serial path) ----
        float R = wave_sum64(q0 + q1);       // lanes>=51 contribute 0 (E=0)
        R = fmaxf(R, 1e-30f);
        invRs = __builtin_amdgcn_rcpf(R) * 0.00390625f;
        log2Rs = __log2f(R);

        Ec.x = __expf(lgB.x + erm0);         // E for step t+1
        Ec.y = __expf(lgB.y + erm1);
        lgB = lgC;
        lgC = *reinterpret_cast<const float2*>(lg + (size_t)min(t + 3, T - 1) * CRF_L + loff);
    }

    // ---- epilogue: out = ln2*Lacc + log(sum_j Q_j * exp(trans[STOP,j])) ----
    float ts0 = TS[CRF_RP * CRF_STOP + (valid ? r0 : 0)];
    float ts1 = TS[CRF_RP * CRF_STOP + (valid ? r1 : 0)];
    float e;
    if (len == 0) {
        e = ((r0 == CRF_START) ? __expf(ts0) : 0.f);   // Q0 = onehot(START)
    } else {
        e = q0 * __expf(ts0) + q1 * __expf(ts1);       // invalid lanes: q=0
    }
    float se = wave_sum64(e);

    if (lane == 0) out[b] = LN2F * Lacc + __logf(se);
}

extern "C" void kernel_launch(void* const* d_in, const int* in_sizes, int n_in,
                              void* d_out, int out_size, void* d_ws, size_t ws_size,
                              hipStream_t stream) {
    const float* logits = (const float*)d_in[0];   // [B, T, L] fp32
    const float* trans  = (const float*)d_in[1];   // [L, L] fp32
    const int*   lens   = (const int*)d_in[2];     // [B] int32
    float* out = (float*)d_out;                    // [B] fp32

    const int B = 512;
    const int T = 512;

    crf_forward_kernel<<<dim3(B), dim3(64), 0, stream>>>(
        logits, trans, lens, out, B, T);
}